// Round 9
// baseline (595.255 us; speedup 1.0000x reference)
//
#include <hip/hip_runtime.h>
#include <math.h>

// ---------------------------------------------------------------------------
// GAT 3-layer + pooling. XCD-sharded gather v3 + conflict-free GEMM LDS.
//  - GEMM LDS tiles stored k-octet-major [q][row][8f16]: fragment ds_read_b128
//    becomes 16 consecutive 16B lanes -> 2-way bank alias (free). Round-8
//    profile showed 3.86M SQ_LDS_BANK_CONFLICT (8-way on row-major frags).
//    global_load_lds lane-contiguity preserved by remapping global addresses.
//  - feat CHUNK-MAJOR featc[chunk][node][64]; chunk=blockIdx%8 -> XCD-pinned L2.
//  - agg v3: wave = 8 clusters x 8 lanes, cluster owns one node.
//  - edge_weight v2: 16-lane clusters (4 nodes/wave), avg deg 16 -> 4x fewer
//    idle lanes than 64-lane-per-node version.
//  - attn logits fused in GEMM epilogue; pooling segmented (gid sorted).
// ---------------------------------------------------------------------------

typedef _Float16 f16;
typedef __attribute__((ext_vector_type(8))) _Float16 half8;
typedef __attribute__((ext_vector_type(4))) _Float16 half4;
typedef __attribute__((ext_vector_type(4))) float float4v;

union U16 { unsigned short u; _Float16 h; };

#define M_PAD 20096        // 20000 rounded up to 128
#define CHSTRIDE ((size_t)M_PAD * 64)

__device__ inline void gload_lds16(const void* g, void* l) {
    __builtin_amdgcn_global_load_lds((const __attribute__((address_space(1))) unsigned*)g,
                                     (__attribute__((address_space(3))) unsigned*)l,
                                     16, 0, 0);
}

// ----------------------------- CSR construction ---------------------------

__global__ __launch_bounds__(256) void deg_kernel(const int* __restrict__ dst,
                                                  int* __restrict__ deg, int E) {
    int e = blockIdx.x * 256 + threadIdx.x;
    if (e < E) atomicAdd(&deg[dst[e]], 1);
}

// scan + (fused) graph-segment binary search
__global__ __launch_bounds__(1024) void scan_kernel(const int* __restrict__ deg,
                                                    int* __restrict__ row_off,
                                                    const int* __restrict__ gid,
                                                    int* __restrict__ gstart, int n) {
    __shared__ int sums[1024];
    int t = threadIdx.x;
    if (t <= 64) {   // independent: gstart[g] = lower_bound(gid, g)
        int g = t, lo = 0, hi = n;
        while (lo < hi) {
            int mid = (lo + hi) >> 1;
            if (gid[mid] < g) lo = mid + 1; else hi = mid;
        }
        gstart[g] = lo;
    }
    int CH = (n + 1023) >> 10;
    int base = t * CH;
    int s = 0;
    for (int i = 0; i < CH; ++i) { int idx = base + i; if (idx < n) s += deg[idx]; }
    sums[t] = s;
    __syncthreads();
    for (int off = 1; off < 1024; off <<= 1) {
        int v = (t >= off) ? sums[t - off] : 0;
        __syncthreads();
        sums[t] += v;
        __syncthreads();
    }
    int run = (t == 0) ? 0 : sums[t - 1];
    for (int i = 0; i < CH; ++i) {
        int idx = base + i;
        if (idx < n) { row_off[idx] = run; run += deg[idx]; }
    }
    if (t == 1023) row_off[n] = run;
}

__global__ __launch_bounds__(256) void fill_kernel(const int* __restrict__ src,
                                                   const int* __restrict__ dst,
                                                   const int* __restrict__ row_off,
                                                   int* __restrict__ fill,
                                                   int* __restrict__ csr_src, int E) {
    int e = blockIdx.x * 256 + threadIdx.x;
    if (e < E) {
        int d = dst[e];
        int pos = row_off[d] + atomicAdd(&fill[d], 1);
        csr_src[pos] = src[e];
    }
}

// ------------------------------ converts -----------------------------------

__global__ __launch_bounds__(256) void cvt_pad_kernel(const float* __restrict__ x,
                                                      f16* __restrict__ y,
                                                      long n_valid, long n_total) {
    long i = ((long)blockIdx.x * 256 + threadIdx.x) * 4;
    if (i >= n_total) return;
    float4 v = make_float4(0.f, 0.f, 0.f, 0.f);
    if (i < n_valid) v = *(const float4*)&x[i];
    half4 o; o[0] = (f16)v.x; o[1] = (f16)v.y; o[2] = (f16)v.z; o[3] = (f16)v.w;
    *(half4*)&y[i] = o;
}

// zero pad rows [n, M_PAD) of x1 and x2 (512 cols each) in one dispatch
__global__ __launch_bounds__(256) void zero_pad_kernel(f16* __restrict__ x1,
                                                       f16* __restrict__ x2, int n) {
    int total = (M_PAD - n) * 512;
    int idx = (blockIdx.x * 256 + threadIdx.x) * 4;
    if (idx < total) {
        half4 z; z[0] = (f16)0.f; z[1] = (f16)0.f; z[2] = (f16)0.f; z[3] = (f16)0.f;
        *(half4*)&x1[(size_t)n * 512 + idx] = z;
        *(half4*)&x2[(size_t)n * 512 + idx] = z;
    }
}

// Wt[n][k] = (f16) W[k][n].  K,N multiples of 32.  block (32,8)
__global__ __launch_bounds__(256) void transpose_cvt_kernel(const float* __restrict__ W,
                                                            f16* __restrict__ Wt,
                                                            int K, int N) {
    __shared__ float tile[32][33];
    int n0 = blockIdx.x * 32, k0 = blockIdx.y * 32;
    int tx = threadIdx.x, ty = threadIdx.y;
#pragma unroll
    for (int i = 0; i < 32; i += 8)
        tile[ty + i][tx] = W[(size_t)(k0 + ty + i) * N + n0 + tx];
    __syncthreads();
#pragma unroll
    for (int i = 0; i < 32; i += 8)
        Wt[(size_t)(n0 + ty + i) * K + k0 + tx] = (f16)tile[tx][ty + i];
}

// ------------------------------ fp16 MFMA GEMM -----------------------------
// LDS layout k-octet-major: As[q][row][8] (q = k/8 within the 32-wide K tile).
// Staging slot s = j*256 + t maps to (q = s>>7, row = s&127); LDS addr = s*16B
// (lane-contiguous for global_load_lds), global addr = A[(bm+row)*K+k0+q*8].
// Fragment reads: 16 consecutive lanes x 16B -> conflict-free.

__global__ __launch_bounds__(256) void gemm16_kernel(const f16* __restrict__ A,
                                                     const f16* __restrict__ Bt,
                                                     f16* __restrict__ Cc,
                                                     f16* __restrict__ Cr,
                                                     const float* __restrict__ al,
                                                     const float* __restrict__ ar,
                                                     float* __restrict__ el8,
                                                     float* __restrict__ er8,
                                                     int N, int K, int nchunk,
                                                     int nheads, int nvalid) {
    __shared__ f16 As[128 * 32];
    __shared__ f16 Bs[128 * 32];
    __shared__ float elds[2][2][128];   // [el/er][wn-half][row]
    int t = threadIdx.x;
    int w = t >> 6;
    int l = t & 63;
    size_t bm = (size_t)blockIdx.y * 128;
    int bn = blockIdx.x * 128;
    int wm = (w & 1) * 64;
    int wn = (w >> 1) * 64;

    int row_s = t & 127;        // staging row
    int q0 = t >> 7;            // staging k-octet (0..1; +2 for issue 1)
    const f16* ag0 = A + (bm + row_s) * K + q0 * 8;
    const f16* ag1 = ag0 + 16;
    const f16* bg0 = Bt + (size_t)(bn + row_s) * K + q0 * 8;
    const f16* bg1 = bg0 + 16;
    f16* al0 = As + t * 8;
    f16* al1 = As + 2048 + t * 8;
    f16* bl0 = Bs + t * 8;
    f16* bl1 = Bs + 2048 + t * 8;

    float4v acc[4][4];
#pragma unroll
    for (int i = 0; i < 4; ++i)
#pragma unroll
        for (int j = 0; j < 4; ++j) acc[i][j] = (float4v)(0.f);

    int ml = l & 15, q = l >> 4;
    const f16* ap = As + q * 1024 + (wm + ml) * 8;
    const f16* bp = Bs + q * 1024 + (wn + ml) * 8;

    for (int k0 = 0; k0 < K; k0 += 32) {
        gload_lds16(ag0 + k0, al0);
        gload_lds16(ag1 + k0, al1);
        gload_lds16(bg0 + k0, bl0);
        gload_lds16(bg1 + k0, bl1);
        __syncthreads();
        half8 af[4], bf[4];
#pragma unroll
        for (int mt = 0; mt < 4; ++mt) af[mt] = *(const half8*)(ap + mt * 128);
#pragma unroll
        for (int nt = 0; nt < 4; ++nt) bf[nt] = *(const half8*)(bp + nt * 128);
#pragma unroll
        for (int mt = 0; mt < 4; ++mt)
#pragma unroll
            for (int nt = 0; nt < 4; ++nt)
                acc[mt][nt] = __builtin_amdgcn_mfma_f32_16x16x32_f16(bf[nt], af[mt],
                                                                     acc[mt][nt], 0, 0, 0);
        __syncthreads();
    }
    // C stores
#pragma unroll
    for (int mt = 0; mt < 4; ++mt) {
        size_t row = bm + wm + mt * 16 + ml;
#pragma unroll
        for (int nt = 0; nt < 4; ++nt) {
            half4 hv;
#pragma unroll
            for (int r = 0; r < 4; ++r) hv[r] = (f16)acc[mt][nt][r];
            int col = bn + wn + nt * 16 + q * 4;
            if (col < nchunk) {
                *(half4*)&Cc[(size_t)(col >> 6) * CHSTRIDE + row * 64 + (col & 63)] = hv;
            } else {
                *(half4*)&Cr[row * (size_t)(N - nchunk) + (col - nchunk)] = hv;
            }
        }
    }
    // fused attention logits (block column == one head)
    if (al != nullptr && bn < nheads * 128) {
        int hh = bn >> 7;
        float4 a4[4], r4[4];
#pragma unroll
        for (int nt = 0; nt < 4; ++nt) {
            int ci = hh * 128 + wn + nt * 16 + q * 4;
            a4[nt] = *(const float4*)&al[ci];
            r4[nt] = *(const float4*)&ar[ci];
        }
        int wnidx = wn >> 6;
#pragma unroll
        for (int mt = 0; mt < 4; ++mt) {
            float ep = 0.f, rp = 0.f;
#pragma unroll
            for (int nt = 0; nt < 4; ++nt) {
                ep += acc[mt][nt][0] * a4[nt].x + acc[mt][nt][1] * a4[nt].y
                    + acc[mt][nt][2] * a4[nt].z + acc[mt][nt][3] * a4[nt].w;
                rp += acc[mt][nt][0] * r4[nt].x + acc[mt][nt][1] * r4[nt].y
                    + acc[mt][nt][2] * r4[nt].z + acc[mt][nt][3] * r4[nt].w;
            }
            ep += __shfl_xor(ep, 16, 64); ep += __shfl_xor(ep, 32, 64);
            rp += __shfl_xor(rp, 16, 64); rp += __shfl_xor(rp, 32, 64);
            if (q == 0) {
                elds[0][wnidx][wm + mt * 16 + ml] = ep;
                elds[1][wnidx][wm + mt * 16 + ml] = rp;
            }
        }
        __syncthreads();
        int row = t & 127, which = t >> 7;
        long gv = (long)bm + row;
        if (gv < nvalid) {
            float vs = elds[which][0][row] + elds[which][1][row];
            if (which == 0) el8[gv * 8 + hh] = vs;
            else            er8[gv * 8 + hh] = vs;
        }
    }
}

// ------------------------ edge softmax weights v2 --------------------------
// 16-lane clusters, 4 nodes per wave (avg deg 16 -> one batch, no idle half).
// Unnormalized f16 weights head-major + inv8[v][h].

__global__ __launch_bounds__(256, 8) void edge_weight_kernel(
        const float* __restrict__ el8, const float* __restrict__ er8,
        const int* __restrict__ row_off, const int* __restrict__ csr_src,
        unsigned short* __restrict__ wexp, float* __restrict__ inv8,
        int H, int n, int E) {
    int wid = threadIdx.x >> 6, lane = threadIdx.x & 63;
    int c2 = lane >> 4;       // cluster in wave (0..3)
    int sl = lane & 15;       // sublane in cluster
    int v = blockIdx.x * 16 + wid * 4 + c2;
    if (v >= n) return;
    float era[6];
    {
        float4 a = *(const float4*)&er8[(size_t)v * 8];
        float2 b = *(const float2*)&er8[(size_t)v * 8 + 4];
        era[0] = a.x; era[1] = a.y; era[2] = a.z; era[3] = a.w;
        era[4] = b.x; era[5] = b.y;
    }
    int beg = row_off[v], end = row_off[v + 1];
    float lsum[6] = {0.f, 0.f, 0.f, 0.f, 0.f, 0.f};
    for (int pos = beg; pos < end; pos += 16) {
        int cnt = min(16, end - pos);
        int s_l = (sl < cnt) ? csr_src[pos + sl] : 0;
        float4 a = *(const float4*)&el8[(size_t)s_l * 8];
        float2 bq = *(const float2*)&el8[(size_t)s_l * 8 + 4];
        float ee[6] = {a.x, a.y, a.z, a.w, bq.x, bq.y};
#pragma unroll
        for (int h = 0; h < 6; ++h) {
            if (h < H) {
                float lg = ee[h] + era[h];
                lg = (lg >= 0.f) ? lg : 0.2f * lg;
                float wv = __expf(lg);
                if (sl >= cnt) wv = 0.f;
                lsum[h] += wv;
                if (sl < cnt) {
                    U16 uu; uu.h = (f16)wv;
                    wexp[(size_t)h * E + pos + sl] = uu.u;
                }
            }
        }
    }
#pragma unroll
    for (int h = 0; h < 6; ++h)
#pragma unroll
        for (int off = 8; off >= 1; off >>= 1)
            lsum[h] += __shfl_xor(lsum[h], off, 64);   // stays within 16-lane cluster
    if (sl == 0) {
#pragma unroll
        for (int h = 0; h < 6; ++h)
            if (h < H) inv8[(size_t)v * 8 + h] = 1.f / fmaxf(lsum[h], 1e-9f);
    }
}

// ---------------- chunk-sharded aggregation v3 (cluster-owns-node) ---------

__device__ __forceinline__ void agg_chunk_body(
        const f16* __restrict__ fc, const unsigned short* __restrict__ wh,
        const float* __restrict__ inv8, int head,
        const int* __restrict__ row_off, const int* __restrict__ csr_src,
        const f16* __restrict__ res, const float* __restrict__ bias,
        f16* __restrict__ out16, float* __restrict__ out32,
        int n, int width, int act, int chunk,
        int wave_id, int wavestride, int lane) {
    int c = lane >> 3;
    int j = lane & 7;
    int coff = j * 8;
    int cb = chunk * 64 + coff;
    float4 bv0 = *(const float4*)&bias[cb];
    float4 bv1 = *(const float4*)&bias[cb + 4];
    int clbase = lane & 56;

    for (int v0 = wave_id * 8; v0 < n; v0 += wavestride * 8) {
        int v = v0 + c;
        bool valid = (v < n);
        int beg = 0, end = 0;
        if (valid) { beg = row_off[v]; end = row_off[v + 1]; }
        int rounds = end - beg;
        rounds = max(rounds, __shfl_xor(rounds, 8, 64));
        rounds = max(rounds, __shfl_xor(rounds, 16, 64));
        rounds = max(rounds, __shfl_xor(rounds, 32, 64));
        float acc[8] = {0.f, 0.f, 0.f, 0.f, 0.f, 0.f, 0.f, 0.f};
        int s_pf = 0, w_pf = 0;
        for (int r = 0; r < rounds; ++r) {
            if ((r & 7) == 0) {   // refill 8-edge prefetch (lane j holds slot j)
                int pidx = beg + r + j;
                bool ok = pidx < end;
                s_pf = ok ? csr_src[pidx] : 0;
                w_pf = ok ? (int)wh[pidx] : 0;
            }
            int srcl = clbase + (r & 7);
            int s  = __shfl(s_pf, srcl, 64);
            int wi = __shfl(w_pf, srcl, 64);
            U16 uu; uu.u = (unsigned short)wi;
            float wv = (float)uu.h;
            half8 f = *(const half8*)&fc[(size_t)s * 64 + coff];
#pragma unroll
            for (int k = 0; k < 8; ++k) acc[k] += wv * (float)f[k];
        }
        if (valid) {
            float inv = inv8[(size_t)v * 8 + head];
            float ox[8];
#pragma unroll
            for (int k = 0; k < 8; ++k) ox[k] = acc[k] * inv;
            size_t base = (size_t)v * width + cb;
            if (res) {
                half8 rr = *(const half8*)&res[base];
#pragma unroll
                for (int k = 0; k < 8; ++k) ox[k] += (float)rr[k];
            }
            ox[0] += bv0.x; ox[1] += bv0.y; ox[2] += bv0.z; ox[3] += bv0.w;
            ox[4] += bv1.x; ox[5] += bv1.y; ox[6] += bv1.z; ox[7] += bv1.w;
            if (act) {
#pragma unroll
                for (int k = 0; k < 8; ++k)
                    ox[k] = (ox[k] > 0.f) ? ox[k] : expm1f(ox[k]);
            }
            if (out16) {
                half8 o;
#pragma unroll
                for (int k = 0; k < 8; ++k) o[k] = (f16)ox[k];
                *(half8*)&out16[base] = o;
            } else {
                *(float4*)&out32[base]     = make_float4(ox[0], ox[1], ox[2], ox[3]);
                *(float4*)&out32[base + 4] = make_float4(ox[4], ox[5], ox[6], ox[7]);
            }
        }
    }
}

__global__ __launch_bounds__(256, 8) void agg_chunk_kernel(
        const f16* __restrict__ featc, const unsigned short* __restrict__ wexp,
        const float* __restrict__ inv8,
        const int* __restrict__ row_off, const int* __restrict__ csr_src,
        const f16* __restrict__ res, const float* __restrict__ bias,
        f16* __restrict__ out16, float* __restrict__ out32,
        int n, int nchunks, int width, int E, int act) {
    int wid = threadIdx.x >> 6, lane = threadIdx.x & 63;
    int b = blockIdx.x;
    {   // phase 1: chunks 0..7, 256 blocks (1024 waves) each
        int chunk = b & 7;
        agg_chunk_body(featc + (size_t)chunk * CHSTRIDE, wexp + (size_t)(chunk >> 1) * E,
                       inv8, chunk >> 1, row_off, csr_src, res, bias, out16, out32,
                       n, width, act, chunk, (b >> 3) * 4 + wid, 1024, lane);
    }
    if (nchunks > 8) {   // phase 2: chunks 8..11, 512 blocks (2048 waves) each
        int chunk = 8 + (b & 3);
        if (chunk < nchunks)
            agg_chunk_body(featc + (size_t)chunk * CHSTRIDE, wexp + (size_t)(chunk >> 1) * E,
                           inv8, chunk >> 1, row_off, csr_src, res, bias, out16, out32,
                           n, width, act, chunk, (b >> 2) * 4 + wid, 2048, lane);
    }
}

// ------------------- pooling: segmented (gid is sorted) --------------------

__global__ __launch_bounds__(128) void mean_pool_kernel(const float* __restrict__ x3,
                                                        float* __restrict__ local, int n) {
    int v = blockIdx.x;
    int d = threadIdx.x;
    const float* p = x3 + (size_t)v * 768;
    float s = 0.f;
#pragma unroll
    for (int h = 0; h < 6; ++h) s += p[h * 128 + d];
    local[(size_t)v * 128 + d] = s * (1.f / 6.f);
}

__global__ __launch_bounds__(256) void graph_pool_kernel(const float* __restrict__ local,
                                                         const int* __restrict__ gstart,
                                                         float* __restrict__ pooled) {
    __shared__ float buf[128];
    int g = blockIdx.x;
    int t = threadIdx.x;
    int c = t & 127;
    int sub = t >> 7;
    int beg = gstart[g], end = gstart[g + 1];
    float s = 0.f;
    for (int v = beg + sub; v < end; v += 2) s += local[(size_t)v * 128 + c];
    if (sub == 1) buf[c] = s;
    __syncthreads();
    if (sub == 0) {
        float tot = s + buf[c];
        float cntf = fmaxf((float)(end - beg), 1.f);
        pooled[g * 128 + c] = tot / cntf;
    }
}

__global__ void final_mlp_kernel(const float* __restrict__ pooled,
                                 const float* __restrict__ Wm,
                                 const float* __restrict__ bm,
                                 float* __restrict__ gout) {
    int g = blockIdx.x;
    int j = threadIdx.x;
    __shared__ float p[128];
    p[j] = pooled[g * 128 + j];
    __syncthreads();
    float s = 0.f;
#pragma unroll 16
    for (int k = 0; k < 128; ++k) s += p[k] * Wm[k * 128 + j];
    gout[g * 128 + j] = s + bm[j];
}

// --------------------------------- driver ----------------------------------

extern "C" void kernel_launch(void* const* d_in, const int* in_sizes, int n_in,
                              void* d_out, int out_size, void* d_ws, size_t ws_size,
                              hipStream_t stream) {
    const float* h     = (const float*)d_in[0];
    const int*   src   = (const int*)d_in[2];
    const int*   dst   = (const int*)d_in[3];
    const int*   gid   = (const int*)d_in[4];
    const float* W0    = (const float*)d_in[5];
    const float* al0   = (const float*)d_in[6];
    const float* ar0   = (const float*)d_in[7];
    const float* b0    = (const float*)d_in[8];
    const float* W1    = (const float*)d_in[9];
    const float* al1   = (const float*)d_in[10];
    const float* ar1   = (const float*)d_in[11];
    const float* b1    = (const float*)d_in[12];
    const float* W2    = (const float*)d_in[13];
    const float* al2   = (const float*)d_in[14];
    const float* ar2   = (const float*)d_in[15];
    const float* b2    = (const float*)d_in[16];
    const float* resW2 = (const float*)d_in[17];
    const float* Wm    = (const float*)d_in[18];
    const float* bm    = (const float*)d_in[19];

    const int n = in_sizes[0] / 128;   // 20000
    const int E = in_sizes[2];         // 320000

    size_t off = 0;
    auto take = [&](size_t bytes) -> void* {
        void* p = (char*)d_ws + off;
        off = (off + bytes + 255) & ~(size_t)255;
        return p;
    };
    f16* h16     = (f16*)take((size_t)M_PAD * 128 * 2);
    f16* Wt0     = (f16*)take((size_t)512 * 128 * 2);
    f16* Wt1     = (f16*)take((size_t)512 * 512 * 2);
    f16* Wt2cat  = (f16*)take((size_t)1536 * 512 * 2);    // [W2^T ; resW2^T]
    f16* featc   = (f16*)take((size_t)12 * CHSTRIDE * 2); // chunk-major feat
    f16* res2    = (f16*)take((size_t)M_PAD * 768 * 2);   // row-major residual L2
    f16* x1_16   = (f16*)take((size_t)M_PAD * 512 * 2);
    f16* x2_16   = (f16*)take((size_t)M_PAD * 512 * 2);
    float* x3    = (float*)take((size_t)n * 768 * 4);
    unsigned short* wexp = (unsigned short*)take((size_t)6 * E * 2);
    float* inv8  = (float*)take((size_t)n * 8 * 4);
    float* el8   = (float*)take((size_t)n * 8 * 4);
    float* er8   = (float*)take((size_t)n * 8 * 4);
    int* deg     = (int*)take((size_t)2 * n * 4);  // deg | fillc contiguous (one memset)
    int* fillc   = deg + n;
    int* row_off = (int*)take((size_t)(n + 1) * 4);
    int* csr_src = (int*)take((size_t)E * 4);
    int* gstart  = (int*)take(65 * 4);
    float* pooled = (float*)take(64 * 128 * 4);

    float* out_local  = (float*)d_out;
    float* out_global = (float*)d_out + (size_t)n * 128;

    hipMemsetAsync(deg, 0, (size_t)2 * n * 4, stream);
    zero_pad_kernel<<<(int)(((size_t)(M_PAD - n) * 512 / 4 + 255) / 256), 256, 0, stream>>>(x1_16, x2_16, n);

    {
        long nv = (long)n * 128, nt = (long)M_PAD * 128;
        cvt_pad_kernel<<<(int)((nt / 4 + 255) / 256), 256, 0, stream>>>(h, h16, nv, nt);
    }
    transpose_cvt_kernel<<<dim3(512 / 32, 128 / 32), dim3(32, 8), 0, stream>>>(W0, Wt0, 128, 512);
    transpose_cvt_kernel<<<dim3(512 / 32, 512 / 32), dim3(32, 8), 0, stream>>>(W1, Wt1, 512, 512);
    transpose_cvt_kernel<<<dim3(768 / 32, 512 / 32), dim3(32, 8), 0, stream>>>(W2, Wt2cat, 512, 768);
    transpose_cvt_kernel<<<dim3(768 / 32, 512 / 32), dim3(32, 8), 0, stream>>>(resW2, Wt2cat + (size_t)768 * 512, 512, 768);

    deg_kernel<<<(E + 255) / 256, 256, 0, stream>>>(dst, deg, E);
    scan_kernel<<<1, 1024, 0, stream>>>(deg, row_off, gid, gstart, n);
    fill_kernel<<<(E + 255) / 256, 256, 0, stream>>>(src, dst, row_off, fillc, csr_src, E);

    const int gy = M_PAD / 128;
    const int ew_blocks = (n + 15) / 16;

    // --- layer 0: feat = h16 @ W0 (8 chunks) + fused logits, H=4, elu ---
    gemm16_kernel<<<dim3(512 / 128, gy), 256, 0, stream>>>(h16, Wt0, featc, nullptr,
                                                           al0, ar0, el8, er8, 512, 128, 512, 4, n);
    edge_weight_kernel<<<ew_blocks, 256, 0, stream>>>(el8, er8, row_off, csr_src, wexp, inv8, 4, n, E);
    agg_chunk_kernel<<<2048, 256, 0, stream>>>(featc, wexp, inv8, row_off, csr_src,
                                               nullptr, b0, x1_16, nullptr, n, 8, 512, E, 1);
    // --- layer 1: feat = x1 @ W1 (8 chunks) + fused logits, identity res, elu ---
    gemm16_kernel<<<dim3(512 / 128, gy), 256, 0, stream>>>(x1_16, Wt1, featc, nullptr,
                                                           al1, ar1, el8, er8, 512, 512, 512, 4, n);
    edge_weight_kernel<<<ew_blocks, 256, 0, stream>>>(el8, er8, row_off, csr_src, wexp, inv8, 4, n, E);
    agg_chunk_kernel<<<2048, 256, 0, stream>>>(featc, wexp, inv8, row_off, csr_src,
                                               x1_16, b1, x2_16, nullptr, n, 8, 512, E, 1);
    // --- layer 2: [feat(12 chunks) | res2] = x2 @ [W2|resW2] + fused logits, H=6 ---
    gemm16_kernel<<<dim3(1536 / 128, gy), 256, 0, stream>>>(x2_16, Wt2cat, featc, res2,
                                                            al2, ar2, el8, er8, 1536, 512, 768, 6, n);
    edge_weight_kernel<<<ew_blocks, 256, 0, stream>>>(el8, er8, row_off, csr_src, wexp, inv8, 6, n, E);
    agg_chunk_kernel<<<2048, 256, 0, stream>>>(featc, wexp, inv8, row_off, csr_src,
                                               res2, b2, nullptr, x3, n, 12, 768, E, 0);
    // --- pooling epilogue (atomic-free) ---
    mean_pool_kernel<<<n, 128, 0, stream>>>(x3, out_local, n);
    graph_pool_kernel<<<64, 256, 0, stream>>>(out_local, gstart, pooled);
    final_mlp_kernel<<<64, 128, 0, stream>>>(pooled, Wm, bm, out_global);
}

// Round 10
// 570.383 us; speedup vs baseline: 1.0436x; 1.0436x over previous
//
#include <hip/hip_runtime.h>
#include <math.h>

// ---------------------------------------------------------------------------
// GAT 3-layer + pooling. XCD-sharded gather v3 + XOR-swizzled GEMM LDS.
//  - GEMM LDS: round-8 coalesced staging (4 lanes = one 64B row segment) with
//    XOR-swizzled octet order (slot s holds octet s^((row>>1)&3)). Frag
//    ds_read_b128 lands 2 lanes per bank-quad -> 2-way alias = free.
//    (Round 8: coalesced + 8-way conflicts = 82us. Round 9: conflict-free but
//     64 lines/staging-instr = 97us. This round: both fixed.)
//  - feat CHUNK-MAJOR featc[chunk][node][64]; chunk=blockIdx%8 -> XCD-pinned L2.
//  - agg v3: wave = 8 clusters x 8 lanes, cluster owns one node.
//  - edge_weight v2: 16-lane clusters, 4 nodes/wave.
//  - attn logits fused in GEMM epilogue; pooling segmented (gid sorted).
// ---------------------------------------------------------------------------

typedef _Float16 f16;
typedef __attribute__((ext_vector_type(8))) _Float16 half8;
typedef __attribute__((ext_vector_type(4))) _Float16 half4;
typedef __attribute__((ext_vector_type(4))) float float4v;

union U16 { unsigned short u; _Float16 h; };

#define M_PAD 20096        // 20000 rounded up to 128
#define CHSTRIDE ((size_t)M_PAD * 64)

__device__ inline void gload_lds16(const void* g, void* l) {
    __builtin_amdgcn_global_load_lds((const __attribute__((address_space(1))) unsigned*)g,
                                     (__attribute__((address_space(3))) unsigned*)l,
                                     16, 0, 0);
}

// ----------------------------- CSR construction ---------------------------

__global__ __launch_bounds__(256) void deg_kernel(const int* __restrict__ dst,
                                                  int* __restrict__ deg, int E) {
    int e = blockIdx.x * 256 + threadIdx.x;
    if (e < E) atomicAdd(&deg[dst[e]], 1);
}

// scan + (fused) graph-segment binary search
__global__ __launch_bounds__(1024) void scan_kernel(const int* __restrict__ deg,
                                                    int* __restrict__ row_off,
                                                    const int* __restrict__ gid,
                                                    int* __restrict__ gstart, int n) {
    __shared__ int sums[1024];
    int t = threadIdx.x;
    if (t <= 64) {
        int g = t, lo = 0, hi = n;
        while (lo < hi) {
            int mid = (lo + hi) >> 1;
            if (gid[mid] < g) lo = mid + 1; else hi = mid;
        }
        gstart[g] = lo;
    }
    int CH = (n + 1023) >> 10;
    int base = t * CH;
    int s = 0;
    for (int i = 0; i < CH; ++i) { int idx = base + i; if (idx < n) s += deg[idx]; }
    sums[t] = s;
    __syncthreads();
    for (int off = 1; off < 1024; off <<= 1) {
        int v = (t >= off) ? sums[t - off] : 0;
        __syncthreads();
        sums[t] += v;
        __syncthreads();
    }
    int run = (t == 0) ? 0 : sums[t - 1];
    for (int i = 0; i < CH; ++i) {
        int idx = base + i;
        if (idx < n) { row_off[idx] = run; run += deg[idx]; }
    }
    if (t == 1023) row_off[n] = run;
}

__global__ __launch_bounds__(256) void fill_kernel(const int* __restrict__ src,
                                                   const int* __restrict__ dst,
                                                   const int* __restrict__ row_off,
                                                   int* __restrict__ fill,
                                                   int* __restrict__ csr_src, int E) {
    int e = blockIdx.x * 256 + threadIdx.x;
    if (e < E) {
        int d = dst[e];
        int pos = row_off[d] + atomicAdd(&fill[d], 1);
        csr_src[pos] = src[e];
    }
}

// ------------------------------ converts -----------------------------------

__global__ __launch_bounds__(256) void cvt_pad_kernel(const float* __restrict__ x,
                                                      f16* __restrict__ y,
                                                      long n_valid, long n_total) {
    long i = ((long)blockIdx.x * 256 + threadIdx.x) * 4;
    if (i >= n_total) return;
    float4 v = make_float4(0.f, 0.f, 0.f, 0.f);
    if (i < n_valid) v = *(const float4*)&x[i];
    half4 o; o[0] = (f16)v.x; o[1] = (f16)v.y; o[2] = (f16)v.z; o[3] = (f16)v.w;
    *(half4*)&y[i] = o;
}

// zero pad rows [n, M_PAD) of x1 and x2 (512 cols each) in one dispatch
__global__ __launch_bounds__(256) void zero_pad_kernel(f16* __restrict__ x1,
                                                       f16* __restrict__ x2, int n) {
    int total = (M_PAD - n) * 512;
    int idx = (blockIdx.x * 256 + threadIdx.x) * 4;
    if (idx < total) {
        half4 z; z[0] = (f16)0.f; z[1] = (f16)0.f; z[2] = (f16)0.f; z[3] = (f16)0.f;
        *(half4*)&x1[(size_t)n * 512 + idx] = z;
        *(half4*)&x2[(size_t)n * 512 + idx] = z;
    }
}

// Wt[n][k] = (f16) W[k][n].  K,N multiples of 32.  block (32,8)
__global__ __launch_bounds__(256) void transpose_cvt_kernel(const float* __restrict__ W,
                                                            f16* __restrict__ Wt,
                                                            int K, int N) {
    __shared__ float tile[32][33];
    int n0 = blockIdx.x * 32, k0 = blockIdx.y * 32;
    int tx = threadIdx.x, ty = threadIdx.y;
#pragma unroll
    for (int i = 0; i < 32; i += 8)
        tile[ty + i][tx] = W[(size_t)(k0 + ty + i) * N + n0 + tx];
    __syncthreads();
#pragma unroll
    for (int i = 0; i < 32; i += 8)
        Wt[(size_t)(n0 + ty + i) * K + k0 + tx] = (f16)tile[tx][ty + i];
}

// ------------------------------ fp16 MFMA GEMM -----------------------------
// LDS: As[row][32] row-major, but octets XOR-swizzled within each row:
//   slot s of row r holds global octet s ^ ((r>>1)&3).
// Staging (coalesced): lane t -> row t>>2, slot t&3 -> stages octet
//   (t&3)^((row>>1)&3); 4 lanes of a row cover the same 64B (permuted).
// Frag read: lane (ml,q) reads slot q^((ml>>1)&3) -> each 8-bank quad gets
//   exactly 2 lanes -> conflict-free. Swizzle invariant under mt*16 / wm=64.

__global__ __launch_bounds__(256) void gemm16_kernel(const f16* __restrict__ A,
                                                     const f16* __restrict__ Bt,
                                                     f16* __restrict__ Cc,
                                                     f16* __restrict__ Cr,
                                                     const float* __restrict__ al,
                                                     const float* __restrict__ ar,
                                                     float* __restrict__ el8,
                                                     float* __restrict__ er8,
                                                     int N, int K, int nchunk,
                                                     int nheads, int nvalid) {
    __shared__ f16 As[128 * 32];
    __shared__ f16 Bs[128 * 32];
    __shared__ float elds[2][2][128];   // [el/er][wn-half][row]
    int t = threadIdx.x;
    int w = t >> 6;
    int l = t & 63;
    size_t bm = (size_t)blockIdx.y * 128;
    int bn = blockIdx.x * 128;
    int wm = (w & 1) * 64;
    int wn = (w >> 1) * 64;

    int srow = t >> 2;                        // 0..63
    int sq = (t & 3) ^ ((srow >> 1) & 3);     // swizzled octet to stage
    const f16* ag0 = A + (bm + srow) * K + sq * 8;
    const f16* ag1 = A + (bm + 64 + srow) * K + sq * 8;   // (64+srow)>>1 ≡ srow>>1 (mod 4)
    const f16* bg0 = Bt + (size_t)(bn + srow) * K + sq * 8;
    const f16* bg1 = Bt + (size_t)(bn + 64 + srow) * K + sq * 8;
    f16* al0 = As + t * 8;
    f16* al1 = As + 2048 + t * 8;
    f16* bl0 = Bs + t * 8;
    f16* bl1 = Bs + 2048 + t * 8;

    float4v acc[4][4];
#pragma unroll
    for (int i = 0; i < 4; ++i)
#pragma unroll
        for (int j = 0; j < 4; ++j) acc[i][j] = (float4v)(0.f);

    int ml = l & 15, q = l >> 4;
    int sslot = (q ^ ((ml >> 1) & 3)) * 8;    // swizzled read slot (f16 offset)
    const f16* ap = As + (wm + ml) * 32 + sslot;
    const f16* bp = Bs + (wn + ml) * 32 + sslot;

    for (int k0 = 0; k0 < K; k0 += 32) {
        gload_lds16(ag0 + k0, al0);
        gload_lds16(ag1 + k0, al1);
        gload_lds16(bg0 + k0, bl0);
        gload_lds16(bg1 + k0, bl1);
        __syncthreads();
        half8 af[4], bf[4];
#pragma unroll
        for (int mt = 0; mt < 4; ++mt) af[mt] = *(const half8*)(ap + mt * 16 * 32);
#pragma unroll
        for (int nt = 0; nt < 4; ++nt) bf[nt] = *(const half8*)(bp + nt * 16 * 32);
#pragma unroll
        for (int mt = 0; mt < 4; ++mt)
#pragma unroll
            for (int nt = 0; nt < 4; ++nt)
                acc[mt][nt] = __builtin_amdgcn_mfma_f32_16x16x32_f16(bf[nt], af[mt],
                                                                     acc[mt][nt], 0, 0, 0);
        __syncthreads();
    }
    // C stores
#pragma unroll
    for (int mt = 0; mt < 4; ++mt) {
        size_t row = bm + wm + mt * 16 + ml;
#pragma unroll
        for (int nt = 0; nt < 4; ++nt) {
            half4 hv;
#pragma unroll
            for (int r = 0; r < 4; ++r) hv[r] = (f16)acc[mt][nt][r];
            int col = bn + wn + nt * 16 + q * 4;
            if (col < nchunk) {
                *(half4*)&Cc[(size_t)(col >> 6) * CHSTRIDE + row * 64 + (col & 63)] = hv;
            } else {
                *(half4*)&Cr[row * (size_t)(N - nchunk) + (col - nchunk)] = hv;
            }
        }
    }
    // fused attention logits (block column == one head)
    if (al != nullptr && bn < nheads * 128) {
        int hh = bn >> 7;
        float4 a4[4], r4[4];
#pragma unroll
        for (int nt = 0; nt < 4; ++nt) {
            int ci = hh * 128 + wn + nt * 16 + q * 4;
            a4[nt] = *(const float4*)&al[ci];
            r4[nt] = *(const float4*)&ar[ci];
        }
        int wnidx = wn >> 6;
#pragma unroll
        for (int mt = 0; mt < 4; ++mt) {
            float ep = 0.f, rp = 0.f;
#pragma unroll
            for (int nt = 0; nt < 4; ++nt) {
                ep += acc[mt][nt][0] * a4[nt].x + acc[mt][nt][1] * a4[nt].y
                    + acc[mt][nt][2] * a4[nt].z + acc[mt][nt][3] * a4[nt].w;
                rp += acc[mt][nt][0] * r4[nt].x + acc[mt][nt][1] * r4[nt].y
                    + acc[mt][nt][2] * r4[nt].z + acc[mt][nt][3] * r4[nt].w;
            }
            ep += __shfl_xor(ep, 16, 64); ep += __shfl_xor(ep, 32, 64);
            rp += __shfl_xor(rp, 16, 64); rp += __shfl_xor(rp, 32, 64);
            if (q == 0) {
                elds[0][wnidx][wm + mt * 16 + ml] = ep;
                elds[1][wnidx][wm + mt * 16 + ml] = rp;
            }
        }
        __syncthreads();
        int row = t & 127, which = t >> 7;
        long gv = (long)bm + row;
        if (gv < nvalid) {
            float vs = elds[which][0][row] + elds[which][1][row];
            if (which == 0) el8[gv * 8 + hh] = vs;
            else            er8[gv * 8 + hh] = vs;
        }
    }
}

// ------------------------ edge softmax weights v2 --------------------------

__global__ __launch_bounds__(256, 8) void edge_weight_kernel(
        const float* __restrict__ el8, const float* __restrict__ er8,
        const int* __restrict__ row_off, const int* __restrict__ csr_src,
        unsigned short* __restrict__ wexp, float* __restrict__ inv8,
        int H, int n, int E) {
    int wid = threadIdx.x >> 6, lane = threadIdx.x & 63;
    int c2 = lane >> 4;
    int sl = lane & 15;
    int v = blockIdx.x * 16 + wid * 4 + c2;
    if (v >= n) return;
    float era[6];
    {
        float4 a = *(const float4*)&er8[(size_t)v * 8];
        float2 b = *(const float2*)&er8[(size_t)v * 8 + 4];
        era[0] = a.x; era[1] = a.y; era[2] = a.z; era[3] = a.w;
        era[4] = b.x; era[5] = b.y;
    }
    int beg = row_off[v], end = row_off[v + 1];
    float lsum[6] = {0.f, 0.f, 0.f, 0.f, 0.f, 0.f};
    for (int pos = beg; pos < end; pos += 16) {
        int cnt = min(16, end - pos);
        int s_l = (sl < cnt) ? csr_src[pos + sl] : 0;
        float4 a = *(const float4*)&el8[(size_t)s_l * 8];
        float2 bq = *(const float2*)&el8[(size_t)s_l * 8 + 4];
        float ee[6] = {a.x, a.y, a.z, a.w, bq.x, bq.y};
#pragma unroll
        for (int h = 0; h < 6; ++h) {
            if (h < H) {
                float lg = ee[h] + era[h];
                lg = (lg >= 0.f) ? lg : 0.2f * lg;
                float wv = __expf(lg);
                if (sl >= cnt) wv = 0.f;
                lsum[h] += wv;
                if (sl < cnt) {
                    U16 uu; uu.h = (f16)wv;
                    wexp[(size_t)h * E + pos + sl] = uu.u;
                }
            }
        }
    }
#pragma unroll
    for (int h = 0; h < 6; ++h)
#pragma unroll
        for (int off = 8; off >= 1; off >>= 1)
            lsum[h] += __shfl_xor(lsum[h], off, 64);
    if (sl == 0) {
#pragma unroll
        for (int h = 0; h < 6; ++h)
            if (h < H) inv8[(size_t)v * 8 + h] = 1.f / fmaxf(lsum[h], 1e-9f);
    }
}

// ---------------- chunk-sharded aggregation v3 (cluster-owns-node) ---------

__device__ __forceinline__ void agg_chunk_body(
        const f16* __restrict__ fc, const unsigned short* __restrict__ wh,
        const float* __restrict__ inv8, int head,
        const int* __restrict__ row_off, const int* __restrict__ csr_src,
        const f16* __restrict__ res, const float* __restrict__ bias,
        f16* __restrict__ out16, float* __restrict__ out32,
        int n, int width, int act, int chunk,
        int wave_id, int wavestride, int lane) {
    int c = lane >> 3;
    int j = lane & 7;
    int coff = j * 8;
    int cb = chunk * 64 + coff;
    float4 bv0 = *(const float4*)&bias[cb];
    float4 bv1 = *(const float4*)&bias[cb + 4];
    int clbase = lane & 56;

    for (int v0 = wave_id * 8; v0 < n; v0 += wavestride * 8) {
        int v = v0 + c;
        bool valid = (v < n);
        int beg = 0, end = 0;
        if (valid) { beg = row_off[v]; end = row_off[v + 1]; }
        int rounds = end - beg;
        rounds = max(rounds, __shfl_xor(rounds, 8, 64));
        rounds = max(rounds, __shfl_xor(rounds, 16, 64));
        rounds = max(rounds, __shfl_xor(rounds, 32, 64));
        float acc[8] = {0.f, 0.f, 0.f, 0.f, 0.f, 0.f, 0.f, 0.f};
        int s_pf = 0, w_pf = 0;
        for (int r = 0; r < rounds; ++r) {
            if ((r & 7) == 0) {
                int pidx = beg + r + j;
                bool ok = pidx < end;
                s_pf = ok ? csr_src[pidx] : 0;
                w_pf = ok ? (int)wh[pidx] : 0;
            }
            int srcl = clbase + (r & 7);
            int s  = __shfl(s_pf, srcl, 64);
            int wi = __shfl(w_pf, srcl, 64);
            U16 uu; uu.u = (unsigned short)wi;
            float wv = (float)uu.h;
            half8 f = *(const half8*)&fc[(size_t)s * 64 + coff];
#pragma unroll
            for (int k = 0; k < 8; ++k) acc[k] += wv * (float)f[k];
        }
        if (valid) {
            float inv = inv8[(size_t)v * 8 + head];
            float ox[8];
#pragma unroll
            for (int k = 0; k < 8; ++k) ox[k] = acc[k] * inv;
            size_t base = (size_t)v * width + cb;
            if (res) {
                half8 rr = *(const half8*)&res[base];
#pragma unroll
                for (int k = 0; k < 8; ++k) ox[k] += (float)rr[k];
            }
            ox[0] += bv0.x; ox[1] += bv0.y; ox[2] += bv0.z; ox[3] += bv0.w;
            ox[4] += bv1.x; ox[5] += bv1.y; ox[6] += bv1.z; ox[7] += bv1.w;
            if (act) {
#pragma unroll
                for (int k = 0; k < 8; ++k)
                    ox[k] = (ox[k] > 0.f) ? ox[k] : expm1f(ox[k]);
            }
            if (out16) {
                half8 o;
#pragma unroll
                for (int k = 0; k < 8; ++k) o[k] = (f16)ox[k];
                *(half8*)&out16[base] = o;
            } else {
                *(float4*)&out32[base]     = make_float4(ox[0], ox[1], ox[2], ox[3]);
                *(float4*)&out32[base + 4] = make_float4(ox[4], ox[5], ox[6], ox[7]);
            }
        }
    }
}

__global__ __launch_bounds__(256, 8) void agg_chunk_kernel(
        const f16* __restrict__ featc, const unsigned short* __restrict__ wexp,
        const float* __restrict__ inv8,
        const int* __restrict__ row_off, const int* __restrict__ csr_src,
        const f16* __restrict__ res, const float* __restrict__ bias,
        f16* __restrict__ out16, float* __restrict__ out32,
        int n, int nchunks, int width, int E, int act) {
    int wid = threadIdx.x >> 6, lane = threadIdx.x & 63;
    int b = blockIdx.x;
    {   // phase 1: chunks 0..7
        int chunk = b & 7;
        agg_chunk_body(featc + (size_t)chunk * CHSTRIDE, wexp + (size_t)(chunk >> 1) * E,
                       inv8, chunk >> 1, row_off, csr_src, res, bias, out16, out32,
                       n, width, act, chunk, (b >> 3) * 4 + wid, 1024, lane);
    }
    if (nchunks > 8) {   // phase 2: chunks 8..11
        int chunk = 8 + (b & 3);
        if (chunk < nchunks)
            agg_chunk_body(featc + (size_t)chunk * CHSTRIDE, wexp + (size_t)(chunk >> 1) * E,
                           inv8, chunk >> 1, row_off, csr_src, res, bias, out16, out32,
                           n, width, act, chunk, (b >> 2) * 4 + wid, 2048, lane);
    }
}

// ------------------- pooling: segmented (gid is sorted) --------------------

__global__ __launch_bounds__(128) void mean_pool_kernel(const float* __restrict__ x3,
                                                        float* __restrict__ local, int n) {
    int v = blockIdx.x;
    int d = threadIdx.x;
    const float* p = x3 + (size_t)v * 768;
    float s = 0.f;
#pragma unroll
    for (int h = 0; h < 6; ++h) s += p[h * 128 + d];
    local[(size_t)v * 128 + d] = s * (1.f / 6.f);
}

__global__ __launch_bounds__(256) void graph_pool_kernel(const float* __restrict__ local,
                                                         const int* __restrict__ gstart,
                                                         float* __restrict__ pooled) {
    __shared__ float buf[128];
    int g = blockIdx.x;
    int t = threadIdx.x;
    int c = t & 127;
    int sub = t >> 7;
    int beg = gstart[g], end = gstart[g + 1];
    float s = 0.f;
    for (int v = beg + sub; v < end; v += 2) s += local[(size_t)v * 128 + c];
    if (sub == 1) buf[c] = s;
    __syncthreads();
    if (sub == 0) {
        float tot = s + buf[c];
        float cntf = fmaxf((float)(end - beg), 1.f);
        pooled[g * 128 + c] = tot / cntf;
    }
}

__global__ void final_mlp_kernel(const float* __restrict__ pooled,
                                 const float* __restrict__ Wm,
                                 const float* __restrict__ bm,
                                 float* __restrict__ gout) {
    int g = blockIdx.x;
    int j = threadIdx.x;
    __shared__ float p[128];
    p[j] = pooled[g * 128 + j];
    __syncthreads();
    float s = 0.f;
#pragma unroll 16
    for (int k = 0; k < 128; ++k) s += p[k] * Wm[k * 128 + j];
    gout[g * 128 + j] = s + bm[j];
}

// --------------------------------- driver ----------------------------------

extern "C" void kernel_launch(void* const* d_in, const int* in_sizes, int n_in,
                              void* d_out, int out_size, void* d_ws, size_t ws_size,
                              hipStream_t stream) {
    const float* h     = (const float*)d_in[0];
    const int*   src   = (const int*)d_in[2];
    const int*   dst   = (const int*)d_in[3];
    const int*   gid   = (const int*)d_in[4];
    const float* W0    = (const float*)d_in[5];
    const float* al0   = (const float*)d_in[6];
    const float* ar0   = (const float*)d_in[7];
    const float* b0    = (const float*)d_in[8];
    const float* W1    = (const float*)d_in[9];
    const float* al1   = (const float*)d_in[10];
    const float* ar1   = (const float*)d_in[11];
    const float* b1    = (const float*)d_in[12];
    const float* W2    = (const float*)d_in[13];
    const float* al2   = (const float*)d_in[14];
    const float* ar2   = (const float*)d_in[15];
    const float* b2    = (const float*)d_in[16];
    const float* resW2 = (const float*)d_in[17];
    const float* Wm    = (const float*)d_in[18];
    const float* bm    = (const float*)d_in[19];

    const int n = in_sizes[0] / 128;   // 20000
    const int E = in_sizes[2];         // 320000

    size_t off = 0;
    auto take = [&](size_t bytes) -> void* {
        void* p = (char*)d_ws + off;
        off = (off + bytes + 255) & ~(size_t)255;
        return p;
    };
    f16* h16     = (f16*)take((size_t)M_PAD * 128 * 2);
    f16* Wt0     = (f16*)take((size_t)512 * 128 * 2);
    f16* Wt1     = (f16*)take((size_t)512 * 512 * 2);
    f16* Wt2cat  = (f16*)take((size_t)1536 * 512 * 2);    // [W2^T ; resW2^T]
    f16* featc   = (f16*)take((size_t)12 * CHSTRIDE * 2); // chunk-major feat
    f16* res2    = (f16*)take((size_t)M_PAD * 768 * 2);   // row-major residual L2
    f16* x1_16   = (f16*)take((size_t)M_PAD * 512 * 2);
    f16* x2_16   = (f16*)take((size_t)M_PAD * 512 * 2);
    float* x3    = (float*)take((size_t)n * 768 * 4);
    unsigned short* wexp = (unsigned short*)take((size_t)6 * E * 2);
    float* inv8  = (float*)take((size_t)n * 8 * 4);
    float* el8   = (float*)take((size_t)n * 8 * 4);
    float* er8   = (float*)take((size_t)n * 8 * 4);
    int* deg     = (int*)take((size_t)2 * n * 4);  // deg | fillc contiguous
    int* fillc   = deg + n;
    int* row_off = (int*)take((size_t)(n + 1) * 4);
    int* csr_src = (int*)take((size_t)E * 4);
    int* gstart  = (int*)take(65 * 4);
    float* pooled = (float*)take(64 * 128 * 4);

    float* out_local  = (float*)d_out;
    float* out_global = (float*)d_out + (size_t)n * 128;

    hipMemsetAsync(deg, 0, (size_t)2 * n * 4, stream);
    zero_pad_kernel<<<(int)(((size_t)(M_PAD - n) * 512 / 4 + 255) / 256), 256, 0, stream>>>(x1_16, x2_16, n);

    {
        long nv = (long)n * 128, nt = (long)M_PAD * 128;
        cvt_pad_kernel<<<(int)((nt / 4 + 255) / 256), 256, 0, stream>>>(h, h16, nv, nt);
    }
    transpose_cvt_kernel<<<dim3(512 / 32, 128 / 32), dim3(32, 8), 0, stream>>>(W0, Wt0, 128, 512);
    transpose_cvt_kernel<<<dim3(512 / 32, 512 / 32), dim3(32, 8), 0, stream>>>(W1, Wt1, 512, 512);
    transpose_cvt_kernel<<<dim3(768 / 32, 512 / 32), dim3(32, 8), 0, stream>>>(W2, Wt2cat, 512, 768);
    transpose_cvt_kernel<<<dim3(768 / 32, 512 / 32), dim3(32, 8), 0, stream>>>(resW2, Wt2cat + (size_t)768 * 512, 512, 768);

    deg_kernel<<<(E + 255) / 256, 256, 0, stream>>>(dst, deg, E);
    scan_kernel<<<1, 1024, 0, stream>>>(deg, row_off, gid, gstart, n);
    fill_kernel<<<(E + 255) / 256, 256, 0, stream>>>(src, dst, row_off, fillc, csr_src, E);

    const int gy = M_PAD / 128;
    const int ew_blocks = (n + 15) / 16;

    // --- layer 0: feat = h16 @ W0 (8 chunks) + fused logits, H=4, elu ---
    gemm16_kernel<<<dim3(512 / 128, gy), 256, 0, stream>>>(h16, Wt0, featc, nullptr,
                                                           al0, ar0, el8, er8, 512, 128, 512, 4, n);
    edge_weight_kernel<<<ew_blocks, 256, 0, stream>>>(el8, er8, row_off, csr_src, wexp, inv8, 4, n, E);
    agg_chunk_kernel<<<2048, 256, 0, stream>>>(featc, wexp, inv8, row_off, csr_src,
                                               nullptr, b0, x1_16, nullptr, n, 8, 512, E, 1);
    // --- layer 1: feat = x1 @ W1 (8 chunks) + fused logits, identity res, elu ---
    gemm16_kernel<<<dim3(512 / 128, gy), 256, 0, stream>>>(x1_16, Wt1, featc, nullptr,
                                                           al1, ar1, el8, er8, 512, 512, 512, 4, n);
    edge_weight_kernel<<<ew_blocks, 256, 0, stream>>>(el8, er8, row_off, csr_src, wexp, inv8, 4, n, E);
    agg_chunk_kernel<<<2048, 256, 0, stream>>>(featc, wexp, inv8, row_off, csr_src,
                                               x1_16, b1, x2_16, nullptr, n, 8, 512, E, 1);
    // --- layer 2: [feat(12 chunks) | res2] = x2 @ [W2|resW2] + fused logits, H=6 ---
    gemm16_kernel<<<dim3(1536 / 128, gy), 256, 0, stream>>>(x2_16, Wt2cat, featc, res2,
                                                            al2, ar2, el8, er8, 1536, 512, 768, 6, n);
    edge_weight_kernel<<<ew_blocks, 256, 0, stream>>>(el8, er8, row_off, csr_src, wexp, inv8, 6, n, E);
    agg_chunk_kernel<<<2048, 256, 0, stream>>>(featc, wexp, inv8, row_off, csr_src,
                                               res2, b2, nullptr, x3, n, 12, 768, E, 0);
    // --- pooling epilogue (atomic-free) ---
    mean_pool_kernel<<<n, 128, 0, stream>>>(x3, out_local, n);
    graph_pool_kernel<<<64, 256, 0, stream>>>(out_local, gstart, pooled);
    final_mlp_kernel<<<64, 128, 0, stream>>>(pooled, Wm, bm, out_global);
}